// Round 7
// baseline (35.826 us; speedup 1.0000x reference)
//
#include <hip/hip_runtime.h>

// JaggedAppend: out = concat_i( values[seg_i] ++ suffix_mat[i] )
// R7: fixed 4-tile split per segment. grid = 4*B blocks of 256 threads.
// seg = blockIdx>>2, tile t = blockIdx&3 covers value range
// [t*1024, min((t+1)*1024, seg_len)). seg_len < 3072 always, so tile 3 never
// holds values -> tile 3 owns the 256-float suffix row. Every block is <=1
// float4-iteration per thread: uniform granularity, no binary search, O(1)
// segment lookup. Phase identity (new_start - prev_old = seg*1024B) makes
// src/dst share alignment mod 16B for every tile.

#define SUF 256
#define NTHR 256
#define TILE 1024  // floats per tile

typedef float floatx4 __attribute__((ext_vector_type(4)));

__global__ __launch_bounds__(NTHR) void
jagged_append_tiled(const float* __restrict__ values,
                    const int* __restrict__ prefix_sum,
                    const float* __restrict__ suffix,
                    float* __restrict__ out,
                    int B) {
    const int seg = blockIdx.x >> 2;
    const int t   = blockIdx.x & 3;
    const int tid = threadIdx.x;
    if (seg >= B) return;

    const int prev_old = (seg > 0) ? prefix_sum[seg - 1] : 0;
    const int end_old  = prefix_sum[seg];
    const int seg_len  = end_old - prev_old;
    const int new_start = prev_old + seg * SUF;

    if (t == 3) {
        // Suffix row: 256 floats, one per thread, coalesced.
        const float* __restrict__ sfx = suffix + seg * SUF;
        float* __restrict__ sdst = out + new_start + seg_len;
        sdst[tid] = sfx[tid];
        return;
    }

    // Value tile [t0, t1) within the segment.
    const int t0 = t * TILE;
    int t1 = t0 + TILE;
    if (t1 > seg_len) t1 = seg_len;
    if (t0 >= t1) return;
    const int n = t1 - t0;

    const float* __restrict__ src = values + prev_old + t0;
    float* __restrict__ dst = out + new_start + t0;

    // Scalar head to reach 16B alignment (src/dst share phase).
    int head = (4 - (((unsigned)(size_t)dst >> 2) & 3)) & 3;
    if (head > n) head = n;
    if (tid < head) dst[tid] = src[tid];

    // Aligned float4 body: <=1 iteration per thread (TILE/4 = 256 = NTHR).
    const int nvec = (n - head) >> 2;
    if (tid < nvec) {
        const floatx4* __restrict__ vs = (const floatx4*)(src + head);
        floatx4* __restrict__ vd = (floatx4*)(dst + head);
        vd[tid] = vs[tid];
    }

    // Scalar tail (<=3 elems).
    const int tail = head + (nvec << 2);
    if (tid < n - tail) dst[tail + tid] = src[tail + tid];
}

extern "C" void kernel_launch(void* const* d_in, const int* in_sizes, int n_in,
                              void* d_out, int out_size, void* d_ws, size_t ws_size,
                              hipStream_t stream) {
    const float* values     = (const float*)d_in[0];
    const int*   prefix_sum = (const int*)d_in[1];
    const float* suffix     = (const float*)d_in[2];
    float* out = (float*)d_out;

    const int B = in_sizes[1];  // 8192 segments

    jagged_append_tiled<<<4 * B, NTHR, 0, stream>>>(values, prefix_sum, suffix,
                                                    out, B);
}

// Round 8
// 30.243 us; speedup vs baseline: 1.1846x; 1.1846x over previous
//
#include <hip/hip_runtime.h>

// JaggedAppend: out = concat_i( values[seg_i] ++ suffix_mat[i] )
// R8 = R2 winner (one block per segment group, block=256, float4 interior)
//  + vectorized suffix copy (dst 16B-aligned stores, src via 16B memcpy loads
//    -> global_load_dwordx4, only 4B alignment required on gfx950)
//  + 2 segments per block (grid B/2): amortizes the serial prefix_sum scalar
//    loads over 2x the copy work, halves block count.
// Phase identity: new_start - prev_old = seg*SUF (1024B), so values-src and
// out-dst share alignment phase mod 16B for every segment.

#define SUF 256
#define NTHR 256

typedef float floatx4 __attribute__((ext_vector_type(4)));

__device__ __forceinline__ void copy_same_phase(const float* __restrict__ src,
                                                float* __restrict__ dst,
                                                int n, int tid) {
    // Requires: src and dst share alignment phase mod 16B.
    int head = (4 - (((unsigned)(size_t)dst >> 2) & 3)) & 3;
    if (head > n) head = n;
    if (tid < head) dst[tid] = src[tid];
    const int nvec = (n - head) >> 2;
    const floatx4* __restrict__ vs = (const floatx4*)(src + head);
    floatx4* __restrict__ vd = (floatx4*)(dst + head);
    for (int v = tid; v < nvec; v += NTHR) vd[v] = vs[v];
    for (int i = head + (nvec << 2) + tid; i < n; i += NTHR) dst[i] = src[i];
}

__device__ __forceinline__ void copy_suffix(const float* __restrict__ sfx,
                                            float* __restrict__ dst, int tid) {
    // n = SUF = 256. dst phase arbitrary; align STORES to 16B, loads are
    // dword-aligned dwordx4 via memcpy (legal + fast on gfx950).
    const int head = (4 - (((unsigned)(size_t)dst >> 2) & 3)) & 3;  // 0..3
    if (tid < head) dst[tid] = sfx[tid];
    const int nvec = (SUF - head) >> 2;  // 63 or 64
    if (tid < nvec) {
        floatx4 v;
        __builtin_memcpy(&v, sfx + head + tid * 4, 16);
        *(floatx4*)(dst + head + tid * 4) = v;
    }
    const int tail = head + (nvec << 2);
    if (tid < SUF - tail) dst[tail + tid] = sfx[tail + tid];
}

__global__ __launch_bounds__(NTHR) void
jagged_append_kernel(const float* __restrict__ values,
                     const int* __restrict__ prefix_sum,
                     const float* __restrict__ suffix,
                     float* __restrict__ out,
                     int B) {
    const int tid = threadIdx.x;
    const int seg0 = blockIdx.x * 2;
    if (seg0 >= B) return;

    const int ps_m1 = (seg0 > 0) ? prefix_sum[seg0 - 1] : 0;
    const int ps0   = prefix_sum[seg0];

    // ---- segment seg0 ----
    {
        const int seg_len = ps0 - ps_m1;
        float* __restrict__ dst = out + ps_m1 + seg0 * SUF;
        copy_same_phase(values + ps_m1, dst, seg_len, tid);
        copy_suffix(suffix + seg0 * SUF, dst + seg_len, tid);
    }

    // ---- segment seg0+1 ----
    const int seg1 = seg0 + 1;
    if (seg1 < B) {
        const int ps1 = prefix_sum[seg1];
        const int seg_len = ps1 - ps0;
        float* __restrict__ dst = out + ps0 + seg1 * SUF;
        copy_same_phase(values + ps0, dst, seg_len, tid);
        copy_suffix(suffix + seg1 * SUF, dst + seg_len, tid);
    }
}

extern "C" void kernel_launch(void* const* d_in, const int* in_sizes, int n_in,
                              void* d_out, int out_size, void* d_ws, size_t ws_size,
                              hipStream_t stream) {
    const float* values     = (const float*)d_in[0];
    const int*   prefix_sum = (const int*)d_in[1];
    const float* suffix     = (const float*)d_in[2];
    float* out = (float*)d_out;

    const int B = in_sizes[1];  // 8192 segments
    const int nblocks = (B + 1) / 2;

    jagged_append_kernel<<<nblocks, NTHR, 0, stream>>>(values, prefix_sum,
                                                       suffix, out, B);
}

// Round 9
// 29.061 us; speedup vs baseline: 1.2328x; 1.0407x over previous
//
#include <hip/hip_runtime.h>

// JaggedAppend: out = concat_i( values[seg_i] ++ suffix_mat[i] )
// FINAL (= R2 winner, best of 8 structural probes at 28.98 us ~ 5.2 TB/s
// combined, ~92% of the 6.29 TB/s copy ceiling net of launch overhead).
// One block per segment, block=256. prefix_sum is the INCLUSIVE prefix sum
// of old segment lengths (int32). Output segment i starts at
// prefix_sum[i-1] + i*SUF.
//
// Vectorization: new_start - prev_old = seg*SUF (256 floats = 1024 B), so
// src (values+prev_old) and dst (out+new_start) have identical alignment
// phase mod 16 B. One shared scalar head of <=3 elems aligns both, then the
// interior is aligned float4 on both sides.
//
// Probed and rejected (all neutral or worse): nontemporal stores (29.6),
// 4-deep ILP unroll + block=128 (30.0), balanced flat output decomposition
// w/ binary search (34.9), fixed 4-tile split (35.8), 2 segs/block +
// vectorized suffix (30.2).

#define SUF 256

__global__ void jagged_append_kernel(const float* __restrict__ values,
                                     const int* __restrict__ prefix_sum,
                                     const float* __restrict__ suffix,
                                     float* __restrict__ out,
                                     int B) {
    const int seg = blockIdx.x;
    if (seg >= B) return;
    const int tid = threadIdx.x;
    const int nthr = blockDim.x;

    const long long prev_old = (seg > 0) ? (long long)prefix_sum[seg - 1] : 0ll;
    const long long end_old  = (long long)prefix_sum[seg];
    const long long seg_len  = end_old - prev_old;
    const long long new_start = prev_old + (long long)seg * SUF;

    const float* __restrict__ src = values + prev_old;
    float* __restrict__ dst = out + new_start;

    // Scalar head to reach 16B alignment (same phase on src and dst).
    long long head = (4 - (new_start & 3)) & 3;
    if (head > seg_len) head = seg_len;
    if (tid < head) dst[tid] = src[tid];

    // Aligned float4 interior.
    const long long nvec = (seg_len - head) >> 2;
    const float4* __restrict__ vsrc = (const float4*)(src + head);
    float4* __restrict__ vdst = (float4*)(dst + head);
    for (long long v = tid; v < nvec; v += nthr) {
        vdst[v] = vsrc[v];
    }

    // Scalar tail (<=3 elems).
    const long long tail_start = head + (nvec << 2);
    for (long long i = tail_start + tid; i < seg_len; i += nthr) {
        dst[i] = src[i];
    }

    // Suffix row: 256 floats, src aligned but dst phase arbitrary -> scalar.
    const float* __restrict__ sfx = suffix + (long long)seg * SUF;
    float* __restrict__ sdst = dst + seg_len;
    for (int i = tid; i < SUF; i += nthr) {
        sdst[i] = sfx[i];
    }
}

extern "C" void kernel_launch(void* const* d_in, const int* in_sizes, int n_in,
                              void* d_out, int out_size, void* d_ws, size_t ws_size,
                              hipStream_t stream) {
    const float* values     = (const float*)d_in[0];
    const int*   prefix_sum = (const int*)d_in[1];
    const float* suffix     = (const float*)d_in[2];
    float* out = (float*)d_out;

    const int B = in_sizes[1];  // 8192 segments

    jagged_append_kernel<<<B, 256, 0, stream>>>(values, prefix_sum, suffix, out, B);
}